// Round 2
// baseline (3669.909 us; speedup 1.0000x reference)
//
#include <hip/hip_runtime.h>

// A2M (LaneGCN map-agent attention). All tensors fp32 (per reference).
// ws layout: xA, xB, xC — each N*128 fp32 (32.77 MB), total 98.3 MB.

#define EPB 8   // edges per block in edge_kernel

__device__ __forceinline__ float wave_sum(float v) {
#pragma unroll
    for (int o = 32; o > 0; o >>= 1) v += __shfl_down(v, o, 64);
    return v;
}

// ---------------- meta fuse: x = relu(GN(cat(feat,turn,ctrl,inter) @ mw^T)) ----------------
__global__ __launch_bounds__(128) void meta_kernel(
    const float* __restrict__ feat, const float* __restrict__ turn,
    const float* __restrict__ ctrl, const float* __restrict__ inter,
    const float* __restrict__ mw, const float* __restrict__ mg, const float* __restrict__ mb,
    float* __restrict__ out)
{
    __shared__ __align__(16) float sin_[132];
    __shared__ float sred[4];
    const int row = blockIdx.x;
    const int j = threadIdx.x;
    const int lane = j & 63, wid = j >> 6;

    sin_[j] = feat[(size_t)row * 128 + j];
    if (j < 2) sin_[128 + j] = turn[(size_t)row * 2 + j];
    if (j == 2) sin_[130] = ctrl[row];
    if (j == 3) sin_[131] = inter[row];
    __syncthreads();

    const float* wr = mw + (size_t)j * 132;
    float acc = 0.f;
#pragma unroll
    for (int k = 0; k < 132; k += 4) {
        const float4 w4 = *(const float4*)(wr + k);
        const float4 a4 = *(const float4*)(&sin_[k]);
        acc = fmaf(w4.x, a4.x, fmaf(w4.y, a4.y, fmaf(w4.z, a4.z, fmaf(w4.w, a4.w, acc))));
    }
    float s = wave_sum(acc), s2 = wave_sum(acc * acc);
    if (lane == 0) { sred[wid] = s; sred[2 + wid] = s2; }
    __syncthreads();
    s = sred[0] + sred[1]; s2 = sred[2] + sred[3];
    const float mu = s * (1.f / 128.f);
    const float var = s2 * (1.f / 128.f) - mu * mu;
    float y = (acc - mu) * rsqrtf(var + 1e-5f) * mg[j] + mb[j];
    out[(size_t)row * 128 + j] = fmaxf(y, 0.f);
}

// ---------------- node GEMM: out = [relu]([GN](X @ W^T) [+res]) ----------------
template<bool DO_GN, bool DO_RES, bool DO_RELU>
__global__ __launch_bounds__(128) void node_gemm(
    const float* __restrict__ X, const float* __restrict__ W,
    const float* __restrict__ g, const float* __restrict__ b,
    const float* __restrict__ res, float* __restrict__ out)
{
    __shared__ __align__(16) float sx[128];
    __shared__ float sred[4];
    const int row = blockIdx.x;
    const int j = threadIdx.x;
    const int lane = j & 63, wid = j >> 6;

    sx[j] = X[(size_t)row * 128 + j];
    __syncthreads();

    const float* wr = W + (size_t)j * 128;
    float acc = 0.f;
#pragma unroll
    for (int k = 0; k < 128; k += 8) {
        const float4 w0 = *(const float4*)(wr + k);
        const float4 w1 = *(const float4*)(wr + k + 4);
        const float4 a0 = *(const float4*)(&sx[k]);
        const float4 a1 = *(const float4*)(&sx[k + 4]);
        acc = fmaf(w0.x, a0.x, fmaf(w0.y, a0.y,
              fmaf(w0.z, a0.z, fmaf(w0.w, a0.w,
              fmaf(w1.x, a1.x, fmaf(w1.y, a1.y,
              fmaf(w1.z, a1.z, fmaf(w1.w, a1.w, acc))))))));
    }
    float y = acc;
    if (DO_GN) {
        float s = wave_sum(acc), s2 = wave_sum(acc * acc);
        if (lane == 0) { sred[wid] = s; sred[2 + wid] = s2; }
        __syncthreads();
        s = sred[0] + sred[1]; s2 = sred[2] + sred[3];
        const float mu = s * (1.f / 128.f);
        const float var = s2 * (1.f / 128.f) - mu * mu;
        y = (acc - mu) * rsqrtf(var + 1e-5f) * g[j] + b[j];
    }
    if (DO_RES) y += res[(size_t)row * 128 + j];
    if (DO_RELU) y = fmaxf(y, 0.f);
    out[(size_t)row * 128 + j] = y;
}

// ---------------- row GN + relu ----------------
__global__ __launch_bounds__(128) void rownorm_relu(
    const float* __restrict__ X, const float* __restrict__ g, const float* __restrict__ b,
    float* __restrict__ out)
{
    __shared__ float sred[4];
    const int row = blockIdx.x;
    const int j = threadIdx.x;
    const int lane = j & 63, wid = j >> 6;
    const float v = X[(size_t)row * 128 + j];
    float s = wave_sum(v), s2 = wave_sum(v * v);
    if (lane == 0) { sred[wid] = s; sred[2 + wid] = s2; }
    __syncthreads();
    s = sred[0] + sred[1]; s2 = sred[2] + sred[3];
    const float mu = s * (1.f / 128.f);
    const float var = s2 * (1.f / 128.f) - mu * mu;
    float y = (v - mu) * rsqrtf(var + 1e-5f) * g[j] + b[j];
    out[(size_t)row * 128 + j] = fmaxf(y, 0.f);
}

// ---------------- edge kernel: full per-edge pipeline + scatter atomicAdd ----------------
__global__ __launch_bounds__(128) void edge_kernel(
    const int E,
    const int* __restrict__ hi, const int* __restrict__ wi,
    const float* __restrict__ mc, const float* __restrict__ ac,
    const float* __restrict__ X, const float* __restrict__ agents,
    const float* __restrict__ dw1, const float* __restrict__ db1,
    const float* __restrict__ dw2, const float* __restrict__ dg2, const float* __restrict__ db2,
    const float* __restrict__ qw, const float* __restrict__ qg, const float* __restrict__ qb,
    const float* __restrict__ cw1, const float* __restrict__ cg1, const float* __restrict__ cb1,
    const float* __restrict__ cw2,
    float* __restrict__ OUT)
{
    __shared__ __align__(16) float s_cat[EPB][384];   // [d | q | agents]
    __shared__ __align__(16) float s_row[EPB][128];   // d1 / x rows / c1
    __shared__ float s_red[2][2][EPB];
    __shared__ int s_h[EPB], s_w[EPB], s_valid[EPB];
    __shared__ float s_dx[EPB], s_dy[EPB];

    const int j = threadIdx.x;
    const int lane = j & 63, wid = j >> 6;

    if (j < EPB) {
        const int idx = blockIdx.x * EPB + j;
        const int valid = (idx < E) ? 1 : 0;
        int h = 0, w = 0;
        if (valid) { h = hi[idx]; w = wi[idx]; }
        s_h[j] = h; s_w[j] = w; s_valid[j] = valid;
        s_dx[j] = mc[2 * (size_t)h]     - ac[2 * (size_t)w];
        s_dy[j] = mc[2 * (size_t)h + 1] - ac[2 * (size_t)w + 1];
    }
    __syncthreads();

    float acc[EPB];

    auto dotK = [&](const float* base, int ldstride, const float* wrow, int K) {
#pragma unroll
        for (int e = 0; e < EPB; e++) acc[e] = 0.f;
        for (int k = 0; k < K; k += 8) {
            const float4 w0 = *(const float4*)(wrow + k);
            const float4 w1 = *(const float4*)(wrow + k + 4);
#pragma unroll
            for (int e = 0; e < EPB; e++) {
                const float* r = base + e * ldstride + k;
                const float4 a0 = *(const float4*)(r);
                const float4 a1 = *(const float4*)(r + 4);
                acc[e] = fmaf(w0.x, a0.x, fmaf(w0.y, a0.y, fmaf(w0.z, a0.z, fmaf(w0.w, a0.w,
                         fmaf(w1.x, a1.x, fmaf(w1.y, a1.y, fmaf(w1.z, a1.z, fmaf(w1.w, a1.w, acc[e]))))))));
            }
        }
    };

    auto gn_relu = [&](const float* g, const float* b, bool dorelu) {
        float sums[EPB], sqs[EPB];
#pragma unroll
        for (int e = 0; e < EPB; e++) { sums[e] = wave_sum(acc[e]); sqs[e] = wave_sum(acc[e] * acc[e]); }
        if (lane == 0) {
#pragma unroll
            for (int e = 0; e < EPB; e++) { s_red[0][wid][e] = sums[e]; s_red[1][wid][e] = sqs[e]; }
        }
        __syncthreads();
        const float gg = g[j], bb = b[j];
#pragma unroll
        for (int e = 0; e < EPB; e++) {
            const float s = s_red[0][0][e] + s_red[0][1][e];
            const float s2 = s_red[1][0][e] + s_red[1][1][e];
            const float mu = s * (1.f / 128.f);
            const float var = s2 * (1.f / 128.f) - mu * mu;
            float y = (acc[e] - mu) * rsqrtf(var + 1e-5f) * gg + bb;
            acc[e] = dorelu ? fmaxf(y, 0.f) : y;
        }
        __syncthreads();   // protect s_red reuse + order s_row/s_cat rewrites
    };

    // dist phase 1: d1 = relu(d @ dw1^T + db1) -> s_row
    {
        const float2 w2 = *(const float2*)(dw1 + 2 * (size_t)j);
        const float bb = db1[j];
#pragma unroll
        for (int e = 0; e < EPB; e++)
            s_row[e][j] = fmaxf(fmaf(w2.x, s_dx[e], fmaf(w2.y, s_dy[e], bb)), 0.f);
    }
    // agents gather -> s_cat[:, 256:384]
#pragma unroll
    for (int e = 0; e < EPB; e++)
        s_cat[e][256 + j] = agents[(size_t)s_w[e] * 128 + j];
    __syncthreads();

    // d2 = d1 @ dw2^T, GN, relu -> s_cat[:, 0:128]
    dotK(&s_row[0][0], 128, dw2 + (size_t)j * 128, 128);
    gn_relu(dg2, db2, true);
#pragma unroll
    for (int e = 0; e < EPB; e++) s_cat[e][j] = acc[e];
    __syncthreads();

    // x rows -> s_row
#pragma unroll
    for (int e = 0; e < EPB; e++)
        s_row[e][j] = X[(size_t)s_h[e] * 128 + j];
    __syncthreads();

    // q = x @ qw^T, GN, relu -> s_cat[:, 128:256]
    dotK(&s_row[0][0], 128, qw + (size_t)j * 128, 128);
    gn_relu(qg, qb, true);
#pragma unroll
    for (int e = 0; e < EPB; e++) s_cat[e][128 + j] = acc[e];
    __syncthreads();

    // c1 = cat @ cw1^T, GN, relu -> s_row
    dotK(&s_cat[0][0], 384, cw1 + (size_t)j * 384, 384);
    gn_relu(cg1, cb1, true);
#pragma unroll
    for (int e = 0; e < EPB; e++) s_row[e][j] = acc[e];
    __syncthreads();

    // c2 = c1 @ cw2^T -> scatter
    dotK(&s_row[0][0], 128, cw2 + (size_t)j * 128, 128);
#pragma unroll
    for (int e = 0; e < EPB; e++) {
        if (s_valid[e]) atomicAdd(&OUT[(size_t)s_h[e] * 128 + j], acc[e]);
    }
}

extern "C" void kernel_launch(void* const* d_in, const int* in_sizes, int n_in,
                              void* d_out, int out_size, void* d_ws, size_t ws_size,
                              hipStream_t stream)
{
    const float* feat    = (const float*)d_in[0];
    const float* turn    = (const float*)d_in[1];
    const float* ctrl    = (const float*)d_in[2];
    const float* inter   = (const float*)d_in[3];
    const float* agents  = (const float*)d_in[4];
    const float* mc      = (const float*)d_in[5];
    const float* ac      = (const float*)d_in[6];
    const float* meta_w  = (const float*)d_in[7];
    const float* meta_g  = (const float*)d_in[8];
    const float* meta_b  = (const float*)d_in[9];
    const float* dist_w1 = (const float*)d_in[10];
    const float* dist_b1 = (const float*)d_in[11];
    const float* dist_w2 = (const float*)d_in[12];
    const float* dist_g2 = (const float*)d_in[13];
    const float* dist_b2 = (const float*)d_in[14];
    const float* query_w = (const float*)d_in[15];
    const float* query_g = (const float*)d_in[16];
    const float* query_b = (const float*)d_in[17];
    const float* ctx_w1  = (const float*)d_in[18];
    const float* ctx_g1  = (const float*)d_in[19];
    const float* ctx_b1  = (const float*)d_in[20];
    const float* ctx_w2  = (const float*)d_in[21];
    const float* agt_w   = (const float*)d_in[22];
    const float* norm_g  = (const float*)d_in[23];
    const float* norm_b  = (const float*)d_in[24];
    const float* lin_w   = (const float*)d_in[25];
    const float* lin_g   = (const float*)d_in[26];
    const float* lin_b   = (const float*)d_in[27];
    const int*   hi      = (const int*)d_in[28];
    const int*   wi      = (const int*)d_in[29];

    const int E = in_sizes[28];
    const int N = in_sizes[0] / 128;       // 64000 map nodes

    float* xA = (float*)d_ws;
    float* xB = xA + (size_t)N * 128;
    float* xC = xB + (size_t)N * 128;

    meta_kernel<<<N, 128, 0, stream>>>(feat, turn, ctrl, inter, meta_w, meta_g, meta_b, xA);

    for (int i = 0; i < 2; i++) {
        const size_t o128 = (size_t)i * 128;
        const size_t oMM  = (size_t)i * 128 * 128;
        const size_t oC1  = (size_t)i * 128 * 384;

        // xB = xA @ agt_w^T
        node_gemm<false, false, false><<<N, 128, 0, stream>>>(
            xA, agt_w + oMM, nullptr, nullptr, nullptr, xB);

        // edge pipeline, scatter into xB
        edge_kernel<<<(E + EPB - 1) / EPB, 128, 0, stream>>>(
            E, hi, wi, mc, ac, xA, agents,
            dist_w1 + (size_t)i * 128 * 2, dist_b1 + o128,
            dist_w2 + oMM, dist_g2 + o128, dist_b2 + o128,
            query_w + oMM, query_g + o128, query_b + o128,
            ctx_w1 + oC1, ctx_g1 + o128, ctx_b1 + o128,
            ctx_w2 + oMM, xB);

        // xC = relu(GN(xB))
        rownorm_relu<<<N, 128, 0, stream>>>(xB, norm_g + o128, norm_b + o128, xC);

        // out = relu(GN(xC @ lin_w^T) + xA); layer 0 -> xA, layer 1 -> d_out
        float* dst = (i == 0) ? xA : (float*)d_out;
        node_gemm<true, true, true><<<N, 128, 0, stream>>>(
            xC, lin_w + oMM, lin_g + o128, lin_b + o128, xA, dst);
    }
}

// Round 3
// 1193.074 us; speedup vs baseline: 3.0760x; 3.0760x over previous
//
#include <hip/hip_runtime.h>

// A2M (LaneGCN map-agent attention), fp32.
// Factorized: per-edge work = dist-MLP + cw1_d GEMM + cw2 GEMM only; the
// query path and agent/query parts of ctx_w1 are precomputed per-node (Qc)
// and per-agent (Ac). hi is sorted -> atomic run-combining in the scatter.
// ws: xA, xB (N*128 f32 each) + Ac (2048*128). Qc lives in d_out (scratch).

#define NROWS 8
#define EPB 16

__device__ __forceinline__ float wave_sum(float v) {
#pragma unroll
    for (int o = 32; o > 0; o >>= 1) v += __shfl_xor(v, o, 64);
    return v;
}

template<int NE>
__device__ __forceinline__ void dot128(const float (*s)[128], const float* __restrict__ wrow,
                                       float (&acc)[NE]) {
#pragma unroll
    for (int e = 0; e < NE; e++) acc[e] = 0.f;
#pragma unroll 4
    for (int k = 0; k < 128; k += 8) {
        const float4 w0 = *(const float4*)(wrow + k);
        const float4 w1 = *(const float4*)(wrow + k + 4);
#pragma unroll
        for (int e = 0; e < NE; e++) {
            const float4 a0 = *(const float4*)(&s[e][k]);
            const float4 a1 = *(const float4*)(&s[e][k + 4]);
            acc[e] = fmaf(w0.x, a0.x, fmaf(w0.y, a0.y, fmaf(w0.z, a0.z, fmaf(w0.w, a0.w,
                     fmaf(w1.x, a1.x, fmaf(w1.y, a1.y, fmaf(w1.z, a1.z, fmaf(w1.w, a1.w, acc[e]))))))));
        }
    }
}

// GN over 128 channels (2 waves). Enters/leaves with all threads; 2 barriers inside.
template<int NE>
__device__ __forceinline__ void block_gn(float (&acc)[NE],
                                         const float* __restrict__ g, const float* __restrict__ b,
                                         float (*s_red)[2][NE],
                                         int j, int lane, int wid, bool dorelu) {
    float sums[NE], sqs[NE];
#pragma unroll
    for (int e = 0; e < NE; e++) { sums[e] = wave_sum(acc[e]); sqs[e] = wave_sum(acc[e] * acc[e]); }
    if (lane == 0) {
#pragma unroll
        for (int e = 0; e < NE; e++) { s_red[0][wid][e] = sums[e]; s_red[1][wid][e] = sqs[e]; }
    }
    __syncthreads();
    const float gg = g[j], bb = b[j];
#pragma unroll
    for (int e = 0; e < NE; e++) {
        const float s  = s_red[0][0][e] + s_red[0][1][e];
        const float s2 = s_red[1][0][e] + s_red[1][1][e];
        const float mu = s * (1.f / 128.f);
        const float var = s2 * (1.f / 128.f) - mu * mu;
        float y = (acc[e] - mu) * rsqrtf(var + 1e-5f) * gg + bb;
        acc[e] = dorelu ? fmaxf(y, 0.f) : y;
    }
    __syncthreads();
}

// ---------------- meta: xA = relu(GN(cat(feat,turn,ctrl,inter) @ mw^T)) ----------------
__global__ __launch_bounds__(128) void meta_kernel(
    const int N,
    const float* __restrict__ feat, const float* __restrict__ turn,
    const float* __restrict__ ctrl, const float* __restrict__ inter,
    const float* __restrict__ mw, const float* __restrict__ mg, const float* __restrict__ mb,
    float* __restrict__ out)
{
    __shared__ __align__(16) float s_in[NROWS][132];
    __shared__ float s_red[2][2][NROWS];
    const int j = threadIdx.x, lane = j & 63, wid = j >> 6;
    const int row0 = blockIdx.x * NROWS;

#pragma unroll
    for (int e = 0; e < NROWS; e++) {
        const int r = min(row0 + e, N - 1);
        s_in[e][j] = feat[(size_t)r * 128 + j];
    }
    if (j < NROWS * 2) {
        const int e = j >> 1, c = j & 1;
        s_in[e][128 + c] = turn[(size_t)min(row0 + e, N - 1) * 2 + c];
    } else if (j < NROWS * 3) {
        const int e = j - NROWS * 2;
        s_in[e][130] = ctrl[min(row0 + e, N - 1)];
    } else if (j < NROWS * 4) {
        const int e = j - NROWS * 3;
        s_in[e][131] = inter[min(row0 + e, N - 1)];
    }
    __syncthreads();

    const float* wr = mw + (size_t)j * 132;
    float acc[NROWS];
#pragma unroll
    for (int e = 0; e < NROWS; e++) acc[e] = 0.f;
#pragma unroll 4
    for (int k = 0; k < 132; k += 4) {
        const float4 w4 = *(const float4*)(wr + k);
#pragma unroll
        for (int e = 0; e < NROWS; e++) {
            const float4 a4 = *(const float4*)(&s_in[e][k]);
            acc[e] = fmaf(w4.x, a4.x, fmaf(w4.y, a4.y, fmaf(w4.z, a4.z, fmaf(w4.w, a4.w, acc[e]))));
        }
    }
    block_gn<NROWS>(acc, mg, mb, s_red, j, lane, wid, true);
#pragma unroll
    for (int e = 0; e < NROWS; e++) {
        const int r = row0 + e;
        if (r < N) out[(size_t)r * 128 + j] = acc[e];
    }
}

// -------- node_pre: xB = X@agtw^T ; q = relu(GN(X@qw^T)) ; Qc = q@cw1_q^T --------
__global__ __launch_bounds__(128) void node_pre(
    const int N, const float* __restrict__ X,
    const float* __restrict__ agtw,
    const float* __restrict__ qw, const float* __restrict__ qg, const float* __restrict__ qb,
    const float* __restrict__ cw1,
    float* __restrict__ xB, float* __restrict__ Qc)
{
    __shared__ __align__(16) float s_x[NROWS][128];
    __shared__ __align__(16) float s_q[NROWS][128];
    __shared__ float s_red[2][2][NROWS];
    const int j = threadIdx.x, lane = j & 63, wid = j >> 6;
    const int row0 = blockIdx.x * NROWS;

#pragma unroll
    for (int e = 0; e < NROWS; e++)
        s_x[e][j] = X[(size_t)min(row0 + e, N - 1) * 128 + j];
    __syncthreads();

    float acc[NROWS];
    // agt
    dot128<NROWS>(s_x, agtw + (size_t)j * 128, acc);
#pragma unroll
    for (int e = 0; e < NROWS; e++) {
        const int r = row0 + e;
        if (r < N) xB[(size_t)r * 128 + j] = acc[e];
    }
    // q
    dot128<NROWS>(s_x, qw + (size_t)j * 128, acc);
    block_gn<NROWS>(acc, qg, qb, s_red, j, lane, wid, true);
#pragma unroll
    for (int e = 0; e < NROWS; e++) s_q[e][j] = acc[e];
    __syncthreads();
    // Qc
    dot128<NROWS>(s_q, cw1 + (size_t)j * 384 + 128, acc);
#pragma unroll
    for (int e = 0; e < NROWS; e++) {
        const int r = row0 + e;
        if (r < N) Qc[(size_t)r * 128 + j] = acc[e];
    }
}

// -------- agent_pre: Ac = agents @ cw1_a^T (NA rows) --------
__global__ __launch_bounds__(128) void agent_pre(
    const int NA, const float* __restrict__ agents, const float* __restrict__ cw1,
    float* __restrict__ Ac)
{
    __shared__ __align__(16) float s_x[NROWS][128];
    const int j = threadIdx.x;
    const int row0 = blockIdx.x * NROWS;
#pragma unroll
    for (int e = 0; e < NROWS; e++)
        s_x[e][j] = agents[(size_t)min(row0 + e, NA - 1) * 128 + j];
    __syncthreads();
    float acc[NROWS];
    dot128<NROWS>(s_x, cw1 + (size_t)j * 384 + 256, acc);
#pragma unroll
    for (int e = 0; e < NROWS; e++) {
        const int r = row0 + e;
        if (r < NA) Ac[(size_t)r * 128 + j] = acc[e];
    }
}

// -------- edge: dist MLP + c1 = relu(GN(dc + Qc[hi] + Ac[wi])) + c2 -> scatter --------
__global__ __launch_bounds__(128) void edge_kernel(
    const int E,
    const int* __restrict__ hi, const int* __restrict__ wi,
    const float* __restrict__ mc, const float* __restrict__ ac,
    const float* __restrict__ dw1, const float* __restrict__ db1,
    const float* __restrict__ dw2, const float* __restrict__ dg2, const float* __restrict__ db2,
    const float* __restrict__ cw1, const float* __restrict__ cg1, const float* __restrict__ cb1,
    const float* __restrict__ cw2,
    const float* __restrict__ Qc, const float* __restrict__ Ac,
    float* __restrict__ OUT)
{
    __shared__ __align__(16) float s_a[EPB][128];
    __shared__ __align__(16) float s_b[EPB][128];
    __shared__ float s_red[2][2][EPB];
    __shared__ int s_h[EPB], s_w[EPB];
    __shared__ float s_dx[EPB], s_dy[EPB];

    const int j = threadIdx.x, lane = j & 63, wid = j >> 6;

    if (j < EPB) {
        const int idx = blockIdx.x * EPB + j;
        int h = -1, w = 0;
        if (idx < E) { h = hi[idx]; w = wi[idx]; }
        s_h[j] = h; s_w[j] = w;
        const int hl = (h < 0) ? 0 : h;
        s_dx[j] = mc[2 * (size_t)hl]     - ac[2 * (size_t)w];
        s_dy[j] = mc[2 * (size_t)hl + 1] - ac[2 * (size_t)w + 1];
    }
    __syncthreads();

    // prefetch gathers (coalesced 512B rows)
    float qcv[EPB], acv[EPB];
#pragma unroll
    for (int e = 0; e < EPB; e++) {
        const int h = s_h[e];
        const int hl = (h < 0) ? 0 : h;
        qcv[e] = Qc[(size_t)hl * 128 + j];
        acv[e] = Ac[(size_t)s_w[e] * 128 + j];
    }

    // d1 = relu(d @ dw1^T + db1)
    {
        const float2 w2 = *(const float2*)(dw1 + 2 * (size_t)j);
        const float bb = db1[j];
#pragma unroll
        for (int e = 0; e < EPB; e++)
            s_a[e][j] = fmaxf(fmaf(w2.x, s_dx[e], fmaf(w2.y, s_dy[e], bb)), 0.f);
    }
    __syncthreads();

    float acc[EPB];
    // d2 = relu(GN(d1 @ dw2^T))
    dot128<EPB>(s_a, dw2 + (size_t)j * 128, acc);
    block_gn<EPB>(acc, dg2, db2, s_red, j, lane, wid, true);
#pragma unroll
    for (int e = 0; e < EPB; e++) s_b[e][j] = acc[e];
    __syncthreads();

    // c1 = relu(GN(d2 @ cw1_d^T + Qc[hi] + Ac[wi]))
    dot128<EPB>(s_b, cw1 + (size_t)j * 384, acc);
#pragma unroll
    for (int e = 0; e < EPB; e++) acc[e] += qcv[e] + acv[e];
    block_gn<EPB>(acc, cg1, cb1, s_red, j, lane, wid, true);
#pragma unroll
    for (int e = 0; e < EPB; e++) s_a[e][j] = acc[e];
    __syncthreads();

    // c2 = c1 @ cw2^T -> scatter (hi sorted: run-combine equal rows)
    dot128<EPB>(s_a, cw2 + (size_t)j * 128, acc);
    {
        float pend = 0.f; int ph = -1;
#pragma unroll
        for (int e = 0; e < EPB; e++) {
            const int h = s_h[e];
            if (h == ph) { pend += acc[e]; }
            else {
                if (ph >= 0) atomicAdd(&OUT[(size_t)ph * 128 + j], pend);
                ph = h; pend = acc[e];
            }
        }
        if (ph >= 0) atomicAdd(&OUT[(size_t)ph * 128 + j], pend);
    }
}

// -------- post: out = relu(GN_lin(relu(GN_norm(xB)) @ linw^T) + res) --------
__global__ __launch_bounds__(128) void post_kernel(
    const int N, const float* __restrict__ xB,
    const float* __restrict__ ng, const float* __restrict__ nb,
    const float* __restrict__ linw, const float* __restrict__ lg, const float* __restrict__ lb,
    const float* __restrict__ res, float* __restrict__ out)
{
    __shared__ __align__(16) float s_x[NROWS][128];
    __shared__ float s_red[2][2][NROWS];
    const int j = threadIdx.x, lane = j & 63, wid = j >> 6;
    const int row0 = blockIdx.x * NROWS;

    float acc[NROWS];
#pragma unroll
    for (int e = 0; e < NROWS; e++)
        acc[e] = xB[(size_t)min(row0 + e, N - 1) * 128 + j];
    block_gn<NROWS>(acc, ng, nb, s_red, j, lane, wid, true);
#pragma unroll
    for (int e = 0; e < NROWS; e++) s_x[e][j] = acc[e];
    __syncthreads();

    dot128<NROWS>(s_x, linw + (size_t)j * 128, acc);
    block_gn<NROWS>(acc, lg, lb, s_red, j, lane, wid, false);
#pragma unroll
    for (int e = 0; e < NROWS; e++) {
        const int r = row0 + e;
        if (r < N) {
            const float y = acc[e] + res[(size_t)r * 128 + j];
            out[(size_t)r * 128 + j] = fmaxf(y, 0.f);
        }
    }
}

extern "C" void kernel_launch(void* const* d_in, const int* in_sizes, int n_in,
                              void* d_out, int out_size, void* d_ws, size_t ws_size,
                              hipStream_t stream)
{
    const float* feat    = (const float*)d_in[0];
    const float* turn    = (const float*)d_in[1];
    const float* ctrl    = (const float*)d_in[2];
    const float* inter   = (const float*)d_in[3];
    const float* agents  = (const float*)d_in[4];
    const float* mc      = (const float*)d_in[5];
    const float* ac      = (const float*)d_in[6];
    const float* meta_w  = (const float*)d_in[7];
    const float* meta_g  = (const float*)d_in[8];
    const float* meta_b  = (const float*)d_in[9];
    const float* dist_w1 = (const float*)d_in[10];
    const float* dist_b1 = (const float*)d_in[11];
    const float* dist_w2 = (const float*)d_in[12];
    const float* dist_g2 = (const float*)d_in[13];
    const float* dist_b2 = (const float*)d_in[14];
    const float* query_w = (const float*)d_in[15];
    const float* query_g = (const float*)d_in[16];
    const float* query_b = (const float*)d_in[17];
    const float* ctx_w1  = (const float*)d_in[18];
    const float* ctx_g1  = (const float*)d_in[19];
    const float* ctx_b1  = (const float*)d_in[20];
    const float* ctx_w2  = (const float*)d_in[21];
    const float* agt_w   = (const float*)d_in[22];
    const float* norm_g  = (const float*)d_in[23];
    const float* norm_b  = (const float*)d_in[24];
    const float* lin_w   = (const float*)d_in[25];
    const float* lin_g   = (const float*)d_in[26];
    const float* lin_b   = (const float*)d_in[27];
    const int*   hi      = (const int*)d_in[28];
    const int*   wi      = (const int*)d_in[29];

    const int E  = in_sizes[28];
    const int N  = in_sizes[0] / 128;   // 64000
    const int NA = in_sizes[4] / 128;   // 2048

    float* xA = (float*)d_ws;
    float* xB = xA + (size_t)N * 128;
    float* Ac = xB + (size_t)N * 128;   // NA*128 (1 MB)
    float* Qc = (float*)d_out;          // N*128 scratch, overwritten at the end

    const int gN = (N + NROWS - 1) / NROWS;
    const int gA = (NA + NROWS - 1) / NROWS;
    const int gE = (E + EPB - 1) / EPB;

    meta_kernel<<<gN, 128, 0, stream>>>(N, feat, turn, ctrl, inter, meta_w, meta_g, meta_b, xA);

    for (int i = 0; i < 2; i++) {
        const size_t o128 = (size_t)i * 128;
        const size_t oMM  = (size_t)i * 128 * 128;
        const size_t oC1  = (size_t)i * 128 * 384;

        node_pre<<<gN, 128, 0, stream>>>(
            N, xA, agt_w + oMM, query_w + oMM, query_g + o128, query_b + o128,
            ctx_w1 + oC1, xB, Qc);

        agent_pre<<<gA, 128, 0, stream>>>(NA, agents, ctx_w1 + oC1, Ac);

        edge_kernel<<<gE, 128, 0, stream>>>(
            E, hi, wi, mc, ac,
            dist_w1 + (size_t)i * 128 * 2, dist_b1 + o128,
            dist_w2 + oMM, dist_g2 + o128, dist_b2 + o128,
            ctx_w1 + oC1, ctx_g1 + o128, ctx_b1 + o128,
            ctx_w2 + oMM, Qc, Ac, xB);

        float* dst = (i == 0) ? xA : (float*)d_out;
        post_kernel<<<gN, 128, 0, stream>>>(
            N, xB, norm_g + o128, norm_b + o128,
            lin_w + oMM, lin_g + o128, lin_b + o128, xA, dst);
    }
}

// Round 4
// 273.225 us; speedup vs baseline: 13.4318x; 4.3666x over previous
//
#include <hip/hip_runtime.h>

// A2M (LaneGCN map-agent attention) — MFMA bf16 version.
// All GEMMs via v_mfma_f32_16x16x32_bf16 (fp32 accum); GN/scatter/residual fp32.
// ws: xA, xB (N*128 f32), Ac (NA*128 f32), bf16 weight pool (frag-major).
// Qc lives in d_out (f32 scratch, overwritten by final post pass).

typedef __attribute__((ext_vector_type(8))) short short8v;
typedef __attribute__((ext_vector_type(4))) float f32x4;

#define TE 32      // rows per MFMA block
#define NROWS 8    // rows per block in scalar agent_pre

// ---------------- helpers ----------------
__device__ __forceinline__ unsigned short f2b(float f) {
    union { float f; unsigned u; } v; v.f = f;
    return (unsigned short)((v.u + 0x7fffu + ((v.u >> 16) & 1u)) >> 16);
}
__device__ __forceinline__ short8v pack8(const float* v) {
    union { unsigned short s[8]; short8v v8; } u;
#pragma unroll
    for (int i = 0; i < 8; i++) u.s[i] = f2b(v[i]);
    return u.v8;
}
// store 16 fp32 values as bf16 into swizzled A-buffer (LDA in elements)
__device__ __forceinline__ void store_a16(unsigned short* sA, int LDA, int row, int col,
                                          const float* v) {
    const int base = (row * LDA + col) * 2;
    const int sw = (row & 7) << 4;
    *(short8v*)((char*)sA + ((base) ^ sw))      = pack8(v);
    *(short8v*)((char*)sA + ((base + 16) ^ sw)) = pack8(v + 8);
}
// f32 staging buffer accessor (swizzled, 512B rows)
__device__ __forceinline__ float* scp(float* sC, int row, int col) {
    const int byte = ((row * 128 + col) * 4) ^ (((row >> 2) & 3) << 5);
    return (float*)((char*)sC + byte);
}
__device__ __forceinline__ void read_c16(float* sC, int e, int g, float* v) {
#pragma unroll
    for (int q = 0; q < 4; q++)
        *(float4*)(v + q * 4) = *(const float4*)scp(sC, e, g * 16 + q * 4);
}
// per-row GN stats over 128 ch: 16 vals/thread, 8 threads per row (g = t&7)
__device__ __forceinline__ float2 gn_stats(const float* v) {
    float s = 0.f, s2 = 0.f;
#pragma unroll
    for (int i = 0; i < 16; i++) { s += v[i]; s2 += v[i] * v[i]; }
    s += __shfl_xor(s, 1, 64); s2 += __shfl_xor(s2, 1, 64);
    s += __shfl_xor(s, 2, 64); s2 += __shfl_xor(s2, 2, 64);
    s += __shfl_xor(s, 4, 64); s2 += __shfl_xor(s2, 4, 64);
    const float mu = s * (1.f / 128.f);
    const float var = s2 * (1.f / 128.f) - mu * mu;
    return make_float2(mu, rsqrtf(var + 1e-5f));
}

// 4-wave 32xK @ K^T->32x128 GEMM. A: bf16 LDS (swizzled). W: frag-major bf16 pool.
template<int NK>
__device__ __forceinline__ void gemm_tile(const unsigned short* sA, int LDA,
                                          const unsigned short* __restrict__ Wf,
                                          f32x4 (&acc)[2][2], int t) {
    const int w = t >> 6, l = t & 63;
    const int lm = l & 15, lk = l >> 4;
#pragma unroll
    for (int mt = 0; mt < 2; mt++)
#pragma unroll
        for (int nt = 0; nt < 2; nt++) acc[mt][nt] = (f32x4){0.f, 0.f, 0.f, 0.f};
#pragma unroll
    for (int kk = 0; kk < NK; kk++) {
        short8v a[2], b[2];
#pragma unroll
        for (int mt = 0; mt < 2; mt++) {
            const int row = mt * 16 + lm;
            const int byte = ((row * LDA + kk * 32 + lk * 8) * 2) ^ ((row & 7) << 4);
            a[mt] = *(const short8v*)((const char*)sA + byte);
        }
#pragma unroll
        for (int nt = 0; nt < 2; nt++) {
            const int gnt = w * 2 + nt;
            b[nt] = *(const short8v*)(Wf + ((size_t)(gnt * NK + kk) * 64 + l) * 8);
        }
#pragma unroll
        for (int mt = 0; mt < 2; mt++)
#pragma unroll
            for (int nt = 0; nt < 2; nt++)
                acc[mt][nt] = __builtin_amdgcn_mfma_f32_16x16x32_bf16(a[mt], b[nt], acc[mt][nt], 0, 0, 0);
    }
}
// write C to swizzled f32 staging
__device__ __forceinline__ void cwrite(float* sC, const f32x4 (&acc)[2][2], int t) {
    const int w = t >> 6, l = t & 63;
    const int ln = l & 15, lr = l >> 4;
#pragma unroll
    for (int mt = 0; mt < 2; mt++)
#pragma unroll
        for (int nt = 0; nt < 2; nt++)
#pragma unroll
            for (int r = 0; r < 4; r++)
                *scp(sC, mt * 16 + lr * 4 + r, w * 32 + nt * 16 + ln) = acc[mt][nt][r];
}
// write C straight to global [row][128] f32
__device__ __forceinline__ void cstore_global(float* dst, int nrows, int row0,
                                              const f32x4 (&acc)[2][2], int t) {
    const int w = t >> 6, l = t & 63;
    const int ln = l & 15, lr = l >> 4;
#pragma unroll
    for (int mt = 0; mt < 2; mt++)
#pragma unroll
        for (int r = 0; r < 4; r++) {
            const int row = row0 + mt * 16 + lr * 4 + r;
            if (row < nrows) {
#pragma unroll
                for (int nt = 0; nt < 2; nt++)
                    dst[(size_t)row * 128 + w * 32 + nt * 16 + ln] = acc[mt][nt][r];
            }
        }
}

// ---------------- weight prep: fp32 -> bf16 frag-major pool ----------------
struct PrepJob { const float* src; int dst; int ld; int kmax; int nk; };
struct PrepJobs { PrepJob j[15]; };

__global__ __launch_bounds__(64) void prep_weights(PrepJobs P, unsigned short* __restrict__ pool) {
    const PrepJob J = P.j[blockIdx.y];
    const int f = blockIdx.x;
    if (f >= 8 * J.nk) return;
    const int l = threadIdx.x;
    const int n = (f / J.nk) * 16 + (l & 15);
    const int kb = (f % J.nk) * 32 + (l >> 4) * 8;
    float v[8];
#pragma unroll
    for (int i = 0; i < 8; i++) {
        const int k = kb + i;
        v[i] = (k < J.kmax) ? J.src[(size_t)n * J.ld + k] : 0.f;
    }
    *(short8v*)(pool + J.dst + ((size_t)f * 64 + l) * 8) = pack8(v);
}

// ---------------- meta: xA = relu(GN(cat(feat,turn,ctrl,inter) @ mw^T)) ----------------
__global__ __launch_bounds__(256) void meta_mfma(
    const int N,
    const float* __restrict__ feat, const float* __restrict__ turn,
    const float* __restrict__ ctrl, const float* __restrict__ inter,
    const unsigned short* __restrict__ Wm,
    const float* __restrict__ mg, const float* __restrict__ mb,
    float* __restrict__ out)
{
    __shared__ __align__(16) unsigned short sA[TE * 192];
    __shared__ __align__(16) float sC[TE * 128];
    const int t = threadIdx.x;
    const int row0 = blockIdx.x * TE;
    const int e = t >> 3, g = t & 7;
    const int r = min(row0 + e, N - 1);
    {
        float v[16];
        const float* src = feat + (size_t)r * 128 + g * 16;
#pragma unroll
        for (int q = 0; q < 4; q++) *(float4*)(v + q * 4) = *(const float4*)(src + q * 4);
        store_a16(sA, 192, e, g * 16, v);
    }
    if (t < TE) {
        const int rr = min(row0 + t, N - 1);
        float v[64];
#pragma unroll
        for (int i = 0; i < 64; i++) v[i] = 0.f;
        v[0] = turn[(size_t)rr * 2];
        v[1] = turn[(size_t)rr * 2 + 1];
        v[2] = ctrl[rr];
        v[3] = inter[rr];
#pragma unroll
        for (int q = 0; q < 4; q++) store_a16(sA, 192, t, 128 + q * 16, v + q * 16);
    }
    __syncthreads();
    f32x4 acc[2][2];
    gemm_tile<5>(sA, 192, Wm, acc, t);
    cwrite(sC, acc, t);
    __syncthreads();
    float v[16];
    read_c16(sC, e, g, v);
    const float2 st = gn_stats(v);
    if (row0 + e < N) {
        float* dst = out + (size_t)(row0 + e) * 128 + g * 16;
#pragma unroll
        for (int q = 0; q < 4; q++) {
            const float4 g4 = *(const float4*)(mg + g * 16 + q * 4);
            const float4 b4 = *(const float4*)(mb + g * 16 + q * 4);
            float4 y;
            y.x = fmaxf((v[q*4+0] - st.x) * st.y * g4.x + b4.x, 0.f);
            y.y = fmaxf((v[q*4+1] - st.x) * st.y * g4.y + b4.y, 0.f);
            y.z = fmaxf((v[q*4+2] - st.x) * st.y * g4.z + b4.z, 0.f);
            y.w = fmaxf((v[q*4+3] - st.x) * st.y * g4.w + b4.w, 0.f);
            *(float4*)(dst + q * 4) = y;
        }
    }
}

// ---------------- node_pre: xB = X@agt^T; Qc = relu(GN(X@qw^T)) @ cw1_q^T ----------------
__global__ __launch_bounds__(256) void node_pre_mfma(
    const int N, const float* __restrict__ X,
    const unsigned short* __restrict__ Wagt,
    const unsigned short* __restrict__ Wq,
    const float* __restrict__ qg, const float* __restrict__ qb,
    const unsigned short* __restrict__ Wc1q,
    float* __restrict__ xB, float* __restrict__ Qc)
{
    __shared__ __align__(16) unsigned short sA[TE * 128];
    __shared__ __align__(16) float sC[TE * 128];
    const int t = threadIdx.x;
    const int row0 = blockIdx.x * TE;
    const int e = t >> 3, g = t & 7;
    const int r = min(row0 + e, N - 1);
    {
        float v[16];
        const float* src = X + (size_t)r * 128 + g * 16;
#pragma unroll
        for (int q = 0; q < 4; q++) *(float4*)(v + q * 4) = *(const float4*)(src + q * 4);
        store_a16(sA, 128, e, g * 16, v);
    }
    __syncthreads();
    f32x4 acc[2][2];
    gemm_tile<4>(sA, 128, Wagt, acc, t);
    cstore_global(xB, N, row0, acc, t);
    gemm_tile<4>(sA, 128, Wq, acc, t);
    cwrite(sC, acc, t);
    __syncthreads();
    {
        float v[16];
        read_c16(sC, e, g, v);
        const float2 st = gn_stats(v);
        float y[16];
#pragma unroll
        for (int q = 0; q < 4; q++) {
            const float4 g4 = *(const float4*)(qg + g * 16 + q * 4);
            const float4 b4 = *(const float4*)(qb + g * 16 + q * 4);
            y[q*4+0] = fmaxf((v[q*4+0] - st.x) * st.y * g4.x + b4.x, 0.f);
            y[q*4+1] = fmaxf((v[q*4+1] - st.x) * st.y * g4.y + b4.y, 0.f);
            y[q*4+2] = fmaxf((v[q*4+2] - st.x) * st.y * g4.z + b4.z, 0.f);
            y[q*4+3] = fmaxf((v[q*4+3] - st.x) * st.y * g4.w + b4.w, 0.f);
        }
        __syncthreads();           // all reads of sA (GEMM2) done before overwrite
        store_a16(sA, 128, e, g * 16, y);
    }
    __syncthreads();
    gemm_tile<4>(sA, 128, Wc1q, acc, t);
    cstore_global(Qc, N, row0, acc, t);
}

// ---------------- agent_pre (scalar, 2048 rows): Ac = agents @ cw1_a^T ----------------
template<int NE>
__device__ __forceinline__ void dot128(const float (*s)[128], const float* __restrict__ wrow,
                                       float (&acc)[NE]) {
#pragma unroll
    for (int e = 0; e < NE; e++) acc[e] = 0.f;
#pragma unroll 4
    for (int k = 0; k < 128; k += 8) {
        const float4 w0 = *(const float4*)(wrow + k);
        const float4 w1 = *(const float4*)(wrow + k + 4);
#pragma unroll
        for (int e = 0; e < NE; e++) {
            const float4 a0 = *(const float4*)(&s[e][k]);
            const float4 a1 = *(const float4*)(&s[e][k + 4]);
            acc[e] = fmaf(w0.x, a0.x, fmaf(w0.y, a0.y, fmaf(w0.z, a0.z, fmaf(w0.w, a0.w,
                     fmaf(w1.x, a1.x, fmaf(w1.y, a1.y, fmaf(w1.z, a1.z, fmaf(w1.w, a1.w, acc[e]))))))));
        }
    }
}
__global__ __launch_bounds__(128) void agent_pre(
    const int NA, const float* __restrict__ agents, const float* __restrict__ cw1,
    float* __restrict__ Ac)
{
    __shared__ __align__(16) float s_x[NROWS][128];
    const int j = threadIdx.x;
    const int row0 = blockIdx.x * NROWS;
#pragma unroll
    for (int e = 0; e < NROWS; e++)
        s_x[e][j] = agents[(size_t)min(row0 + e, NA - 1) * 128 + j];
    __syncthreads();
    float acc[NROWS];
    dot128<NROWS>(s_x, cw1 + (size_t)j * 384 + 256, acc);
#pragma unroll
    for (int e = 0; e < NROWS; e++) {
        const int r = row0 + e;
        if (r < NA) Ac[(size_t)r * 128 + j] = acc[e];
    }
}

// ---------------- edge: dist MLP -> cw1_d (+Qc[hi]+Ac[wi]) -> cw2 -> scatter ----------------
__global__ __launch_bounds__(256) void edge_mfma(
    const int E,
    const int* __restrict__ hi, const int* __restrict__ wi,
    const float* __restrict__ mc, const float* __restrict__ ac,
    const float* __restrict__ dw1, const float* __restrict__ db1,
    const unsigned short* __restrict__ Wd2, const float* __restrict__ dg2, const float* __restrict__ db2,
    const unsigned short* __restrict__ Wc1d, const float* __restrict__ cg1, const float* __restrict__ cb1,
    const unsigned short* __restrict__ Wc2,
    const float* __restrict__ Qc, const float* __restrict__ Acp,
    float* __restrict__ OUT)
{
    __shared__ __align__(16) unsigned short sA[TE * 128];
    __shared__ __align__(16) float sC[TE * 128];
    __shared__ int s_h[TE], s_w[TE];
    __shared__ float s_dx[TE], s_dy[TE];
    const int t = threadIdx.x;
    if (t < TE) {
        const int idx = blockIdx.x * TE + t;
        int h = -1, w = 0;
        if (idx < E) { h = hi[idx]; w = wi[idx]; }
        s_h[t] = h; s_w[t] = w;
        const int hl = (h < 0) ? 0 : h;
        s_dx[t] = mc[2 * (size_t)hl]     - ac[2 * (size_t)w];
        s_dy[t] = mc[2 * (size_t)hl + 1] - ac[2 * (size_t)w + 1];
    }
    __syncthreads();
    const int e = t >> 3, g = t & 7;
    // gather Qc[hi]+Ac[wi] into 16 regs (coalesced 64B per 8-thread row group)
    float qa[16];
    {
        const int h = (s_h[e] < 0) ? 0 : s_h[e];
        const float* qp = Qc  + (size_t)h * 128 + g * 16;
        const float* ap = Acp + (size_t)s_w[e] * 128 + g * 16;
#pragma unroll
        for (int q = 0; q < 4; q++) {
            const float4 a = *(const float4*)(qp + q * 4);
            const float4 b = *(const float4*)(ap + q * 4);
            qa[q*4+0] = a.x + b.x; qa[q*4+1] = a.y + b.y;
            qa[q*4+2] = a.z + b.z; qa[q*4+3] = a.w + b.w;
        }
    }
    // d1 = relu(dw1 @ (dx,dy) + db1)
    {
        const float dx = s_dx[e], dy = s_dy[e];
        float v[16];
#pragma unroll
        for (int i = 0; i < 16; i++) {
            const int c = g * 16 + i;
            const float2 w2 = *(const float2*)(dw1 + 2 * c);
            v[i] = fmaxf(fmaf(w2.x, dx, fmaf(w2.y, dy, db1[c])), 0.f);
        }
        store_a16(sA, 128, e, g * 16, v);
    }
    __syncthreads();
    f32x4 acc[2][2];
    float v[16], y[16];

    gemm_tile<4>(sA, 128, Wd2, acc, t);
    cwrite(sC, acc, t);
    __syncthreads();
    read_c16(sC, e, g, v);
    {
        const float2 st = gn_stats(v);
#pragma unroll
        for (int q = 0; q < 4; q++) {
            const float4 g4 = *(const float4*)(dg2 + g * 16 + q * 4);
            const float4 b4 = *(const float4*)(db2 + g * 16 + q * 4);
            y[q*4+0] = fmaxf((v[q*4+0] - st.x) * st.y * g4.x + b4.x, 0.f);
            y[q*4+1] = fmaxf((v[q*4+1] - st.x) * st.y * g4.y + b4.y, 0.f);
            y[q*4+2] = fmaxf((v[q*4+2] - st.x) * st.y * g4.z + b4.z, 0.f);
            y[q*4+3] = fmaxf((v[q*4+3] - st.x) * st.y * g4.w + b4.w, 0.f);
        }
    }
    __syncthreads();
    store_a16(sA, 128, e, g * 16, y);
    __syncthreads();

    gemm_tile<4>(sA, 128, Wc1d, acc, t);
    cwrite(sC, acc, t);
    __syncthreads();
    read_c16(sC, e, g, v);
    {
#pragma unroll
        for (int i = 0; i < 16; i++) v[i] += qa[i];
        const float2 st = gn_stats(v);
#pragma unroll
        for (int q = 0; q < 4; q++) {
            const float4 g4 = *(const float4*)(cg1 + g * 16 + q * 4);
            const float4 b4 = *(const float4*)(cb1 + g * 16 + q * 4);
            y[q*4+0] = fmaxf((v[q*4+0] - st.x) * st.y * g4.x + b4.x, 0.f);
            y[q*4+1] = fmaxf((v[q*4+1] - st.x) * st.y * g4.y + b4.y, 0.f);
            y[q*4+2] = fmaxf((v[q*4+2] - st.x) * st.y * g4.z + b4.z, 0.f);
            y[q*4+3] = fmaxf((v[q*4+3] - st.x) * st.y * g4.w + b4.w, 0.f);
        }
    }
    __syncthreads();
    store_a16(sA, 128, e, g * 16, y);
    __syncthreads();

    gemm_tile<4>(sA, 128, Wc2, acc, t);
    cwrite(sC, acc, t);
    __syncthreads();
    // scatter with run-combining (hi sorted)
    {
        const int c = t & 127;
        const int e0 = (t >> 7) * 16;
        float pend = 0.f; int ph = -1;
#pragma unroll
        for (int k = 0; k < 16; k++) {
            const int ee = e0 + k;
            const int h = s_h[ee];
            const float val = *scp(sC, ee, c);
            if (h == ph) pend += val;
            else {
                if (ph >= 0) atomicAdd(&OUT[(size_t)ph * 128 + c], pend);
                ph = h; pend = val;
            }
        }
        if (ph >= 0) atomicAdd(&OUT[(size_t)ph * 128 + c], pend);
    }
}

// ---------------- post: out = relu(GN_lin(relu(GN_norm(xB)) @ lin^T) + res) ----------------
__global__ __launch_bounds__(256) void post_mfma(
    const int N, const float* __restrict__ xB,
    const float* __restrict__ ng, const float* __restrict__ nb,
    const unsigned short* __restrict__ Wlin,
    const float* __restrict__ lg, const float* __restrict__ lb,
    const float* __restrict__ res, float* __restrict__ out)
{
    __shared__ __align__(16) unsigned short sA[TE * 128];
    __shared__ __align__(16) float sC[TE * 128];
    const int t = threadIdx.x;
    const int row0 = blockIdx.x * TE;
    const int e = t >> 3, g = t & 7;
    const int r = min(row0 + e, N - 1);
    {
        float v[16], y[16];
        const float* src = xB + (size_t)r * 128 + g * 16;
#pragma unroll
        for (int q = 0; q < 4; q++) *(float4*)(v + q * 4) = *(const float4*)(src + q * 4);
        const float2 st = gn_stats(v);
#pragma unroll
        for (int q = 0; q < 4; q++) {
            const float4 g4 = *(const float4*)(ng + g * 16 + q * 4);
            const float4 b4 = *(const float4*)(nb + g * 16 + q * 4);
            y[q*4+0] = fmaxf((v[q*4+0] - st.x) * st.y * g4.x + b4.x, 0.f);
            y[q*4+1] = fmaxf((v[q*4+1] - st.x) * st.y * g4.y + b4.y, 0.f);
            y[q*4+2] = fmaxf((v[q*4+2] - st.x) * st.y * g4.z + b4.z, 0.f);
            y[q*4+3] = fmaxf((v[q*4+3] - st.x) * st.y * g4.w + b4.w, 0.f);
        }
        store_a16(sA, 128, e, g * 16, y);
    }
    __syncthreads();
    f32x4 acc[2][2];
    gemm_tile<4>(sA, 128, Wlin, acc, t);
    cwrite(sC, acc, t);
    __syncthreads();
    {
        float v[16];
        read_c16(sC, e, g, v);
        const float2 st = gn_stats(v);
        if (row0 + e < N) {
            const float* rp = res + (size_t)(row0 + e) * 128 + g * 16;
            float* dst = out + (size_t)(row0 + e) * 128 + g * 16;
#pragma unroll
            for (int q = 0; q < 4; q++) {
                const float4 g4 = *(const float4*)(lg + g * 16 + q * 4);
                const float4 b4 = *(const float4*)(lb + g * 16 + q * 4);
                const float4 r4 = *(const float4*)(rp + q * 4);
                float4 y;
                y.x = fmaxf((v[q*4+0] - st.x) * st.y * g4.x + b4.x + r4.x, 0.f);
                y.y = fmaxf((v[q*4+1] - st.x) * st.y * g4.y + b4.y + r4.y, 0.f);
                y.z = fmaxf((v[q*4+2] - st.x) * st.y * g4.z + b4.z + r4.z, 0.f);
                y.w = fmaxf((v[q*4+3] - st.x) * st.y * g4.w + b4.w + r4.w, 0.f);
                *(float4*)(dst + q * 4) = y;
            }
        }
    }
}

extern "C" void kernel_launch(void* const* d_in, const int* in_sizes, int n_in,
                              void* d_out, int out_size, void* d_ws, size_t ws_size,
                              hipStream_t stream)
{
    const float* feat    = (const float*)d_in[0];
    const float* turn    = (const float*)d_in[1];
    const float* ctrl    = (const float*)d_in[2];
    const float* inter   = (const float*)d_in[3];
    const float* agents  = (const float*)d_in[4];
    const float* mc      = (const float*)d_in[5];
    const float* ac      = (const float*)d_in[6];
    const float* meta_w  = (const float*)d_in[7];
    const float* meta_g  = (const float*)d_in[8];
    const float* meta_b  = (const float*)d_in[9];
    const float* dist_w1 = (const float*)d_in[10];
    const float* dist_b1 = (const float*)d_in[11];
    const float* dist_w2 = (const float*)d_in[12];
    const float* dist_g2 = (const float*)d_in[13];
    const float* dist_b2 = (const float*)d_in[14];
    const float* query_w = (const float*)d_in[15];
    const float* query_g = (const float*)d_in[16];
    const float* query_b = (const float*)d_in[17];
    const float* ctx_w1  = (const float*)d_in[18];
    const float* ctx_g1  = (const float*)d_in[19];
    const float* ctx_b1  = (const float*)d_in[20];
    const float* ctx_w2  = (const float*)d_in[21];
    const float* agt_w   = (const float*)d_in[22];
    const float* norm_g  = (const float*)d_in[23];
    const float* norm_b  = (const float*)d_in[24];
    const float* lin_w   = (const float*)d_in[25];
    const float* lin_g   = (const float*)d_in[26];
    const float* lin_b   = (const float*)d_in[27];
    const int*   hi      = (const int*)d_in[28];
    const int*   wi      = (const int*)d_in[29];

    const int E  = in_sizes[28];
    const int N  = in_sizes[0] / 128;   // 64000
    const int NA = in_sizes[4] / 128;   // 2048

    float* xA = (float*)d_ws;
    float* xB = xA + (size_t)N * 128;
    float* Ac = xB + (size_t)N * 128;
    unsigned short* pool = (unsigned short*)(Ac + (size_t)NA * 128);
    float* Qc = (float*)d_out;

    const int FR128  = 8 * 4 * 64 * 8;   // 16384 elems per 128x128 matrix
    const int FRMETA = 8 * 5 * 64 * 8;   // 20480 elems for meta (K padded to 160)

    // --- weight prep jobs ---
    PrepJobs P;
    P.j[0] = { meta_w, 0, 132, 132, 5 };
    for (int i = 0; i < 2; i++) {
        const int b = FRMETA + i * 7 * FR128;
        P.j[1 + i * 7 + 0] = { query_w + (size_t)i * 16384, b + 0 * FR128, 128, 128, 4 };
        P.j[1 + i * 7 + 1] = { agt_w   + (size_t)i * 16384, b + 1 * FR128, 128, 128, 4 };
        P.j[1 + i * 7 + 2] = { dist_w2 + (size_t)i * 16384, b + 2 * FR128, 128, 128, 4 };
        P.j[1 + i * 7 + 3] = { ctx_w1  + (size_t)i * 49152,       b + 3 * FR128, 384, 128, 4 };
        P.j[1 + i * 7 + 4] = { ctx_w1  + (size_t)i * 49152 + 128, b + 4 * FR128, 384, 128, 4 };
        P.j[1 + i * 7 + 5] = { ctx_w2  + (size_t)i * 16384, b + 5 * FR128, 128, 128, 4 };
        P.j[1 + i * 7 + 6] = { lin_w   + (size_t)i * 16384, b + 6 * FR128, 128, 128, 4 };
    }
    prep_weights<<<dim3(40, 15), 64, 0, stream>>>(P, pool);

    const int gN = (N + TE - 1) / TE;
    const int gE = (E + TE - 1) / TE;
    const int gA = (NA + NROWS - 1) / NROWS;

    meta_mfma<<<gN, 256, 0, stream>>>(N, feat, turn, ctrl, inter,
                                      pool, meta_g, meta_b, xA);

    for (int i = 0; i < 2; i++) {
        const size_t o128 = (size_t)i * 128;
        const int b = FRMETA + i * 7 * FR128;
        const unsigned short* Wq   = pool + b + 0 * FR128;
        const unsigned short* Wagt = pool + b + 1 * FR128;
        const unsigned short* Wd2  = pool + b + 2 * FR128;
        const unsigned short* Wc1d = pool + b + 3 * FR128;
        const unsigned short* Wc1q = pool + b + 4 * FR128;
        const unsigned short* Wc2  = pool + b + 5 * FR128;
        const unsigned short* Wlin = pool + b + 6 * FR128;

        node_pre_mfma<<<gN, 256, 0, stream>>>(
            N, xA, Wagt, Wq, query_g + o128, query_b + o128, Wc1q, xB, Qc);

        agent_pre<<<gA, 128, 0, stream>>>(NA, agents, ctx_w1 + (size_t)i * 49152, Ac);

        edge_mfma<<<gE, 256, 0, stream>>>(
            E, hi, wi, mc, ac,
            dist_w1 + (size_t)i * 256, dist_b1 + o128,
            Wd2, dist_g2 + o128, dist_b2 + o128,
            Wc1d, ctx_g1 + o128, ctx_b1 + o128,
            Wc2, Qc, Ac, xB);

        float* dst = (i == 0) ? xA : (float*)d_out;
        post_mfma<<<gN, 256, 0, stream>>>(
            N, xB, norm_g + o128, norm_b + o128,
            Wlin, lin_g + o128, lin_b + o128, xA, dst);
    }
}